// Round 6
// baseline (554.872 us; speedup 1.0000x reference)
//
#include <hip/hip_runtime.h>
#include <stdint.h>
#include <stddef.h>

typedef unsigned short u16;
typedef __attribute__((ext_vector_type(8))) short short8;   // 8 x bf16 MFMA A/B frag
typedef __attribute__((ext_vector_type(4))) float float4v;  // MFMA C/D frag
typedef __attribute__((ext_vector_type(2))) unsigned uint2v;

typedef const __attribute__((address_space(1))) void* gas_p;
typedef __attribute__((address_space(3))) void* las_p;

__device__ __forceinline__ float bf2f(u16 h) {
  union { unsigned u; float f; } v; v.u = ((unsigned)h) << 16; return v.f;
}
__device__ __forceinline__ u16 f2bf(float f) {
  union { float f; unsigned u; } v; v.f = f;
  return (u16)((v.u + 0x7FFFu + ((v.u >> 16) & 1u)) >> 16);
}
// packed f32->bf16 (RNE), gfx950. No builtin exists (m240); inline asm.
__device__ __forceinline__ unsigned cvt_pk_bf16(float lo, float hi) {
  unsigned r;
  asm("v_cvt_pk_bf16_f32 %0, %1, %2" : "=v"(r) : "v"(lo), "v"(hi));
  return r;
}

// ---------------------------------------------------------------------------
__global__ __launch_bounds__(256) void detect_kernel(const u16* __restrict__ src,
                                                     int* __restrict__ flag) {
  __shared__ int cnt[256];
  int c = 0;
  for (int j = 0; j < 256; j++) {
    const u16 w = src[threadIdx.x + j * 256];
    c += (((w >> 7) & 0xFF) == 0xFF) ? 1 : 0;
  }
  cnt[threadIdx.x] = c;
  __syncthreads();
  if (threadIdx.x == 0) {
    int t = 0;
    for (int i = 0; i < 256; i++) t += cnt[i];
    *flag = (t > 0) ? 1 : 0;
  }
}

__global__ __launch_bounds__(256) void cvt_bf16_kernel(const void* __restrict__ src,
                                                       const int* __restrict__ flag,
                                                       u16* __restrict__ dst, int n) {
  const int f = *flag;
  const int stride = gridDim.x * 256;
  for (int i = blockIdx.x * 256 + threadIdx.x; i < n; i += stride)
    dst[i] = f ? f2bf(((const float*)src)[i]) : ((const u16*)src)[i];
}

__global__ __launch_bounds__(256) void cvt_f32_kernel(const void* __restrict__ src,
                                                      const int* __restrict__ flag,
                                                      float* __restrict__ dst, int n) {
  const int f = *flag;
  const int stride = gridDim.x * 256;
  for (int i = blockIdx.x * 256 + threadIdx.x; i < n; i += stride)
    dst[i] = f ? ((const float*)src)[i] : bf2f(((const u16*)src)[i]);
}

__global__ __launch_bounds__(256) void cvt_transpose_kernel(
    const void* __restrict__ src, const int* __restrict__ flag,
    u16* __restrict__ dst, int R, int C) {
  __shared__ u16 tile[64][65];
  const int f = *flag;
  const int c0 = blockIdx.x * 64, r0 = blockIdx.y * 64;
  const int tc = threadIdx.x & 63;
  const int tr0 = (threadIdx.x >> 6) * 16;
#pragma unroll
  for (int i = 0; i < 16; i++) {
    const size_t idx = (size_t)(r0 + tr0 + i) * C + c0 + tc;
    tile[tr0 + i][tc] = f ? f2bf(((const float*)src)[idx]) : ((const u16*)src)[idx];
  }
  __syncthreads();
#pragma unroll
  for (int i = 0; i < 16; i++)
    dst[(size_t)(c0 + tr0 + i) * R + r0 + tc] = tile[tc][tr0 + i];
}

// ---------------------------------------------------------------------------
// C[M][N] = A[M][K] @ Bt[N][K]^T + bias[N]  (bf16 in, fp32 accum)
// ---------------------------------------------------------------------------
__global__ __launch_bounds__(256) void gemm_bt_kernel(
    const u16* __restrict__ A, const u16* __restrict__ Bt,
    const float* __restrict__ bias, void* __restrict__ C,
    int M, int N, int K, int out32) {
  __shared__ u16 As[128 * 64];
  __shared__ u16 Bs[128 * 64];
  const int tid = threadIdx.x;
  const int wave = tid >> 6, lane = tid & 63;
  const int wm = wave & 1, wn = wave >> 1;
  const int m0 = blockIdx.y * 128, n0 = blockIdx.x * 128;
  const int lr = lane >> 3, lc = lane & 7;
  const int quad = lane >> 4, l15 = lane & 15;

  float4v acc[4][4];
#pragma unroll
  for (int t = 0; t < 4; t++)
#pragma unroll
    for (int u = 0; u < 4; u++) acc[t][u] = (float4v){0.f, 0.f, 0.f, 0.f};

  for (int k0 = 0; k0 < K; k0 += 64) {
    __syncthreads();
#pragma unroll
    for (int i = 0; i < 4; i++) {
      const int brow = wave * 32 + i * 8;
      const int row = brow + lr;
      const int cG = lc ^ (row & 7);
      __builtin_amdgcn_global_load_lds(
          (gas_p)(A + (size_t)(m0 + row) * K + k0 + cG * 8),
          (las_p)(As + brow * 64), 16, 0, 0);
      __builtin_amdgcn_global_load_lds(
          (gas_p)(Bt + (size_t)(n0 + row) * K + k0 + cG * 8),
          (las_p)(Bs + brow * 64), 16, 0, 0);
    }
    __syncthreads();
#pragma unroll
    for (int ks = 0; ks < 2; ks++) {
      short8 af[4], bfr[4];
#pragma unroll
      for (int t = 0; t < 4; t++) {
        const int ar = wm * 64 + t * 16 + l15;
        af[t] = *(const short8*)(As + ar * 64 + ((ks * 4 + quad) ^ (ar & 7)) * 8);
        const int br = wn * 64 + t * 16 + l15;
        bfr[t] = *(const short8*)(Bs + br * 64 + ((ks * 4 + quad) ^ (br & 7)) * 8);
      }
#pragma unroll
      for (int t = 0; t < 4; t++)
#pragma unroll
        for (int u = 0; u < 4; u++)
          acc[t][u] = __builtin_amdgcn_mfma_f32_16x16x32_bf16(af[t], bfr[u], acc[t][u], 0, 0, 0);
    }
  }

  const int qr = quad << 2;
#pragma unroll
  for (int t = 0; t < 4; t++) {
    const int mrow = m0 + wm * 64 + t * 16 + qr;
#pragma unroll
    for (int u = 0; u < 4; u++) {
      const int col = n0 + wn * 64 + u * 16 + l15;
      const float bv = bias[col];
#pragma unroll
      for (int r = 0; r < 4; r++) {
        const float val = acc[t][u][r] + bv;
        if (out32) ((float*)C)[(size_t)(mrow + r) * N + col] = val;
        else       ((u16*)C)[(size_t)(mrow + r) * N + col] = f2bf(val);
      }
    }
  }
}

// ---------------------------------------------------------------------------
#define FA_S 2048
#define FA_D 1024
#define FA_LD 3072
#define NEG_BIG (-1e30f)

// ---------------------------------------------------------------------------
// One-shot V pre-transpose: qkv V-region [b,s,h,hd] -> vt[bh][hd][s].
// ---------------------------------------------------------------------------
__global__ __launch_bounds__(256) void vtrans_kernel(const u16* __restrict__ qkv,
                                                     u16* __restrict__ vt) {
  __shared__ __align__(16) u16 tile[64][72];
  const int tid = threadIdx.x;
  const int bh = blockIdx.y, b = bh >> 4, h = bh & 15;
  const int s0 = blockIdx.x * 64;
#pragma unroll
  for (int i = 0; i < 2; i++) {
    const int c = tid + i * 256;
    const int row = c >> 3, col = (c & 7) * 8;
    const int cs = col ^ (((row >> 3) & 7) * 8);
    *(short8*)(&tile[row][cs]) =
        *(const short8*)(qkv + (size_t)(b * FA_S + s0 + row) * FA_LD + 2 * FA_D + h * 64 + col);
  }
  __syncthreads();
#pragma unroll
  for (int i = 0; i < 2; i++) {
    const int c = tid + i * 256;
    const int hd = c >> 3, scol = (c & 7) * 8;
    const int xr = ((scol >> 3) & 7) * 8;
    __align__(16) u16 tmp[8];
#pragma unroll
    for (int j = 0; j < 8; j++) tmp[j] = tile[scol + j][hd ^ xr];
    *(short8*)(vt + (size_t)bh * (64 * FA_S) + (size_t)hd * FA_S + s0 + scol) =
        *(const short8*)tmp;
  }
}

// ---------------------------------------------------------------------------
// Per-tile softmax step (swapped-QK layout: lane owns q=l15, 16 keys).
// ---------------------------------------------------------------------------
__device__ __forceinline__ void fa_softmax(
    float4v s[4], float& m_i, float& l_i, float4v o[4],
    const float* amrow, bool diag, int wq, int quad) {
  float mcur = NEG_BIG;
  if (diag) {
#pragma unroll
    for (int nt = 0; nt < 4; nt++) {
      const float4v amv = *(const float4v*)(amrow + nt * 16 + (quad << 2));
#pragma unroll
      for (int r = 0; r < 4; r++) {
        const int kl = nt * 16 + (quad << 2) + r;
        float v = (kl <= wq) ? s[nt][r] : -10000.0f;
        v += amv[r];
        s[nt][r] = v;
        mcur = fmaxf(mcur, v);
      }
    }
  } else {
#pragma unroll
    for (int nt = 0; nt < 4; nt++) {
      const float4v amv = *(const float4v*)(amrow + nt * 16 + (quad << 2));
#pragma unroll
      for (int r = 0; r < 4; r++) {
        const float v = s[nt][r] + amv[r];
        s[nt][r] = v;
        mcur = fmaxf(mcur, v);
      }
    }
  }
  mcur = fmaxf(mcur, __shfl_xor(mcur, 16, 64));
  mcur = fmaxf(mcur, __shfl_xor(mcur, 32, 64));

  // T13 defer-max: only rescale when the max moved by >8
  if (!__all(mcur <= m_i + 8.f)) {
    const float mn = fmaxf(m_i, mcur);
    const float alpha = __expf(m_i - mn);
    m_i = mn;
    l_i *= alpha;
    float ar[4];
#pragma unroll
    for (int r = 0; r < 4; r++) ar[r] = __shfl(alpha, (quad << 2) + r, 64);
#pragma unroll
    for (int u = 0; u < 4; u++)
#pragma unroll
      for (int r = 0; r < 4; r++) o[u][r] *= ar[r];
  }

  float lsum = 0.f;
#pragma unroll
  for (int nt = 0; nt < 4; nt++)
#pragma unroll
    for (int r = 0; r < 4; r++) {
      const float e = __expf(s[nt][r] - m_i);
      s[nt][r] = e;
      lsum += e;
    }
  lsum += __shfl_xor(lsum, 16, 64);
  lsum += __shfl_xor(lsum, 32, 64);
  l_i += lsum;
}

// P -> own-wave LDS (cvt_pk + b64 writes), then O += P V (vf already in regs).
__device__ __forceinline__ void fa_pv(
    u16* Pw, const float4v s[4], const short8 vf[2][4], float4v o[4],
    int quad, int l15) {
#pragma unroll
  for (int nt = 0; nt < 4; nt++) {
    const unsigned w0 = cvt_pk_bf16(s[nt][0], s[nt][1]);
    const unsigned w1 = cvt_pk_bf16(s[nt][2], s[nt][3]);
    uint2v ww; ww.x = w0; ww.y = w1;
    *(uint2v*)(Pw + l15 * 72 + nt * 16 + (quad << 2)) = ww;
  }
  __builtin_amdgcn_s_setprio(1);
#pragma unroll
  for (int ks = 0; ks < 2; ks++) {
    const short8 pf = *(const short8*)(Pw + l15 * 72 + ks * 32 + quad * 8);
#pragma unroll
    for (int u = 0; u < 4; u++)
      o[u] = __builtin_amdgcn_mfma_f32_16x16x32_bf16(pf, vf[ks][u], o[u], 0, 0, 0);
  }
  __builtin_amdgcn_s_setprio(0);
}

// ---------------------------------------------------------------------------
// Flash attention (causal), fused pair + XCD-local grid (round 4) +
// DIRECT-GLOBAL V fragments (round 5): vt is L2-resident and XCD-local
// (FETCH 37MB measured), so V staging is pure overhead. vf ks=0 issues at
// iteration top, ks=1 after softmax-B -> QK+softmax (~500cy) covers L2
// latency (~250cy). Removes 8 global_load_lds + 8 ds_read_b128 per iter
// and 16KB LDS: 42->25.7KB -> grid's 4 blocks/CU all resident.
// __launch_bounds__(256,4) pins VGPR<=128 for 4 waves/SIMD.
// ---------------------------------------------------------------------------
__global__ __launch_bounds__(256, 4) void flash_kernel(
    const u16* __restrict__ qkv, const u16* __restrict__ vt,
    const float* __restrict__ am, u16* __restrict__ aout) {
  __shared__ u16 Ks[2][64 * 64];   // [key][slot], slot = chunk^(key&7)
  __shared__ u16 Ps[4][16 * 72];   // per-wave P [q=l15][key] (stride 72)

  const int tid = threadIdx.x, wave = tid >> 6, lane = tid & 63;
  const int bh = blockIdx.x, b = bh >> 4, h = bh & 15;   // XCD-local: id%8=bh%8
  const int qp = blockIdx.y;                             // 0..15
  const int qtA = qp, qtB = 31 - qp;                     // qtA < qtB always
  const size_t rowbase = (size_t)b * FA_S;
  const int quad = lane >> 4, l15 = lane & 15;
  const int lr = lane >> 3, lc = lane & 7;
  const int wq = wave * 16 + l15;      // q-local within a 64-row tile
  const float* amrow0 = am + b * FA_S;
  const u16* kbase = qkv + rowbase * FA_LD + FA_D + h * 64;
  // per-lane V^T row pointers (row = u*16+l15, col base = quad*8)
  const u16* vrow[4];
#pragma unroll
  for (int u = 0; u < 4; u++)
    vrow[u] = vt + (size_t)bh * (64 * FA_S) + (size_t)(u * 16 + l15) * FA_S + quad * 8;

  // Q fragments for both tiles, pre-scaled by 1/8 (exact power of 2)
  short8 qfA[2], qfB[2];
#pragma unroll
  for (int t = 0; t < 2; t++) {
    const int qt = t ? qtB : qtA;
    const int qrow = qt * 64 + wq;
    const u16* qp_ = qkv + (rowbase + qrow) * FA_LD + h * 64 + quad * 8;
    __align__(16) u16 t0[8], t1[8];
    *(short8*)t0 = *(const short8*)qp_;
    *(short8*)t1 = *(const short8*)(qp_ + 32);
#pragma unroll
    for (int j = 0; j < 8; j++) {
      t0[j] = f2bf(bf2f(t0[j]) * 0.125f);
      t1[j] = f2bf(bf2f(t1[j]) * 0.125f);
    }
    if (t) { qfB[0] = *(const short8*)t0; qfB[1] = *(const short8*)t1; }
    else   { qfA[0] = *(const short8*)t0; qfA[1] = *(const short8*)t1; }
  }

  float mA = NEG_BIG, lA = 0.f, mB = NEG_BIG, lB = 0.f;
  float4v oA[4], oB[4];
#pragma unroll
  for (int u = 0; u < 4; u++) {
    oA[u] = (float4v){0.f, 0.f, 0.f, 0.f};
    oB[u] = (float4v){0.f, 0.f, 0.f, 0.f};
  }

  int cur = 0;
  // --- prologue: stage K tile kt=0 into buffer 0 ---
#pragma unroll
  for (int i = 0; i < 2; i++) {
    const int brow = wave * 16 + i * 8;
    const int row = brow + lr;
    const int cG = lc ^ (row & 7);
    __builtin_amdgcn_global_load_lds(
        (gas_p)(kbase + (size_t)row * FA_LD + cG * 8),
        (las_p)(Ks[0] + brow * 64), 16, 0, 0);
  }
  __syncthreads();   // drains vmcnt(0): buffer 0 ready

  for (int kt = 0; kt <= qtB; kt++) {
    // --- V fragments ks=0 direct from global (L2-hit; covered by QK+softmax)
    short8 vf[2][4];
#pragma unroll
    for (int u = 0; u < 4; u++)
      vf[0][u] = *(const short8*)(vrow[u] + kt * 64);

    // --- prefetch next K tile into Ks[cur^1] ---
    if (kt < qtB) {
#pragma unroll
      for (int i = 0; i < 2; i++) {
        const int brow = wave * 16 + i * 8;
        const int row = brow + lr;
        const int cG = lc ^ (row & 7);
        __builtin_amdgcn_global_load_lds(
            (gas_p)(kbase + (size_t)((kt + 1) * 64 + row) * FA_LD + cG * 8),
            (las_p)(Ks[cur ^ 1] + brow * 64), 16, 0, 0);
      }
    }
    const u16* Kc = Ks[cur];
    const bool actA = (kt <= qtA);   // wave-uniform

    // --- S^T = K Q^T for both tiles; each kf read feeds A and B ---
    float4v sA[4], sB[4];
#pragma unroll
    for (int nt = 0; nt < 4; nt++) {
      sA[nt] = (float4v){0.f, 0.f, 0.f, 0.f};
      sB[nt] = (float4v){0.f, 0.f, 0.f, 0.f};
    }
    __builtin_amdgcn_s_setprio(1);
#pragma unroll
    for (int ks = 0; ks < 2; ks++) {
#pragma unroll
      for (int nt = 0; nt < 4; nt++) {
        const int kr = nt * 16 + l15;
        const short8 kf = *(const short8*)(Kc + kr * 64 + (((ks * 4 + quad) ^ (kr & 7)) << 3));
        sB[nt] = __builtin_amdgcn_mfma_f32_16x16x32_bf16(kf, qfB[ks], sB[nt], 0, 0, 0);
        if (actA)
          sA[nt] = __builtin_amdgcn_mfma_f32_16x16x32_bf16(kf, qfA[ks], sA[nt], 0, 0, 0);
      }
    }
    __builtin_amdgcn_s_setprio(0);

    // --- softmax per tile ---
    const float* amrow = amrow0 + kt * 64;
    fa_softmax(sB, mB, lB, oB, amrow, kt == qtB, wq, quad);

    // --- V fragments ks=1 (covered by softmax-A before PV) ---
#pragma unroll
    for (int u = 0; u < 4; u++)
      vf[1][u] = *(const short8*)(vrow[u] + kt * 64 + 32);

    if (actA) fa_softmax(sA, mA, lA, oA, amrow, kt == qtA, wq, quad);

    u16* Pw = Ps[wave];
    fa_pv(Pw, sB, vf, oB, quad, l15);            // P_B write -> PV_B
    if (actA) fa_pv(Pw, sA, vf, oA, quad, l15);  // reuse Pw (intra-wave order)

    __syncthreads();
    cur ^= 1;
  }

  // --- epilogues ---
#pragma unroll
  for (int t = 0; t < 2; t++) {
    const float l_i = t ? lB : lA;
    const float4v* o = t ? oB : oA;
    const int qrg = (t ? qtB : qtA) * 64 + wave * 16 + quad * 4;
    float lr_[4];
#pragma unroll
    for (int r = 0; r < 4; r++) lr_[r] = __shfl(l_i, (quad << 2) + r, 64);
#pragma unroll
    for (int u = 0; u < 4; u++) {
      const int col = h * 64 + u * 16 + l15;
#pragma unroll
      for (int r = 0; r < 4; r++) {
        const float val = o[u][r] / lr_[r];
        aout[(rowbase + qrg + r) * FA_D + col] = f2bf(val);
      }
    }
  }
}

// ---------------------------------------------------------------------------
extern "C" void kernel_launch(void* const* d_in, const int* in_sizes, int n_in,
                              void* d_out, int out_size, void* d_ws, size_t ws_size,
                              hipStream_t stream) {
  (void)out_size; (void)ws_size;
  auto find = [&](int count, int def_idx) -> const void* {
    for (int i = 0; i < n_in; i++)
      if (in_sizes[i] == count) return d_in[i];
    return d_in[def_idx];
  };
  const void* x  = find(8388608, 0);
  const void* am = find(8192, 1);
  const void* Wa = find(3145728, 2);
  const void* ba = find(3072, 3);
  const void* Wp = find(1048576, 4);
  const void* bp = find(1024, 5);

  char* ws = (char*)d_ws;
  u16*   x_c  = (u16*)(ws + 0);
  u16*   Wa_t = (u16*)(ws + 16777216);
  u16*   Wp_t = (u16*)(ws + 23068672);
  u16*   qkv  = (u16*)(ws + 25165824);
  u16*   abuf = (u16*)(ws + 75497472);
  float* ba_f = (float*)(ws + 92274688);
  float* bp_f = (float*)(ws + 92286976);
  float* am_f = (float*)(ws + 92291072);
  int*   flag = (int*)(ws + 92323840);
  // V^T reuses the x_c region (dead after the first GEMM, stream-ordered).
  u16*   vt   = (u16*)(ws + 0);

  const int M = 8192, D = 1024;

  detect_kernel<<<1, 256, 0, stream>>>((const u16*)x, flag);
  cvt_bf16_kernel<<<2048, 256, 0, stream>>>(x, flag, x_c, M * D);
  cvt_f32_kernel<<<12, 256, 0, stream>>>(ba, flag, ba_f, 3072);
  cvt_f32_kernel<<<4, 256, 0, stream>>>(bp, flag, bp_f, 1024);
  cvt_f32_kernel<<<32, 256, 0, stream>>>(am, flag, am_f, 4 * FA_S);
  cvt_transpose_kernel<<<dim3(3072 / 64, 1024 / 64), 256, 0, stream>>>(Wa, flag, Wa_t, 1024, 3072);
  cvt_transpose_kernel<<<dim3(1024 / 64, 1024 / 64), 256, 0, stream>>>(Wp, flag, Wp_t, 1024, 1024);

  gemm_bt_kernel<<<dim3(3072 / 128, M / 128), 256, 0, stream>>>(
      x_c, Wa_t, ba_f, qkv, M, 3072, D, 0);
  vtrans_kernel<<<dim3(FA_S / 64, 64), 256, 0, stream>>>(qkv, vt);
  // grid x=bh (64), y=qp (16): wg id % 8 == bh % 8 -> per-bh XCD locality
  flash_kernel<<<dim3(64, 16), 256, 0, stream>>>(qkv, vt, am_f, abuf);
  gemm_bt_kernel<<<dim3(D / 128, M / 128), 256, 0, stream>>>(
      abuf, Wp_t, bp_f, d_out, M, D, D, 1);
}

// Round 7
// 452.613 us; speedup vs baseline: 1.2259x; 1.2259x over previous
//
#include <hip/hip_runtime.h>
#include <stdint.h>
#include <stddef.h>

typedef unsigned short u16;
typedef __attribute__((ext_vector_type(8))) short short8;   // 8 x bf16 MFMA A/B frag
typedef __attribute__((ext_vector_type(4))) float float4v;  // MFMA C/D frag
typedef __attribute__((ext_vector_type(2))) unsigned uint2v;

typedef const __attribute__((address_space(1))) void* gas_p;
typedef __attribute__((address_space(3))) void* las_p;

__device__ __forceinline__ float bf2f(u16 h) {
  union { unsigned u; float f; } v; v.u = ((unsigned)h) << 16; return v.f;
}
__device__ __forceinline__ u16 f2bf(float f) {
  union { float f; unsigned u; } v; v.f = f;
  return (u16)((v.u + 0x7FFFu + ((v.u >> 16) & 1u)) >> 16);
}
// packed f32->bf16 (RNE), gfx950. No builtin exists (m240); inline asm.
__device__ __forceinline__ unsigned cvt_pk_bf16(float lo, float hi) {
  unsigned r;
  asm("v_cvt_pk_bf16_f32 %0, %1, %2" : "=v"(r) : "v"(lo), "v"(hi));
  return r;
}

// ---------------------------------------------------------------------------
__global__ __launch_bounds__(256) void detect_kernel(const u16* __restrict__ src,
                                                     int* __restrict__ flag) {
  __shared__ int cnt[256];
  int c = 0;
  for (int j = 0; j < 256; j++) {
    const u16 w = src[threadIdx.x + j * 256];
    c += (((w >> 7) & 0xFF) == 0xFF) ? 1 : 0;
  }
  cnt[threadIdx.x] = c;
  __syncthreads();
  if (threadIdx.x == 0) {
    int t = 0;
    for (int i = 0; i < 256; i++) t += cnt[i];
    *flag = (t > 0) ? 1 : 0;
  }
}

__global__ __launch_bounds__(256) void cvt_bf16_kernel(const void* __restrict__ src,
                                                       const int* __restrict__ flag,
                                                       u16* __restrict__ dst, int n) {
  const int f = *flag;
  const int stride = gridDim.x * 256;
  for (int i = blockIdx.x * 256 + threadIdx.x; i < n; i += stride)
    dst[i] = f ? f2bf(((const float*)src)[i]) : ((const u16*)src)[i];
}

__global__ __launch_bounds__(256) void cvt_f32_kernel(const void* __restrict__ src,
                                                      const int* __restrict__ flag,
                                                      float* __restrict__ dst, int n) {
  const int f = *flag;
  const int stride = gridDim.x * 256;
  for (int i = blockIdx.x * 256 + threadIdx.x; i < n; i += stride)
    dst[i] = f ? ((const float*)src)[i] : bf2f(((const u16*)src)[i]);
}

__global__ __launch_bounds__(256) void cvt_transpose_kernel(
    const void* __restrict__ src, const int* __restrict__ flag,
    u16* __restrict__ dst, int R, int C) {
  __shared__ u16 tile[64][65];
  const int f = *flag;
  const int c0 = blockIdx.x * 64, r0 = blockIdx.y * 64;
  const int tc = threadIdx.x & 63;
  const int tr0 = (threadIdx.x >> 6) * 16;
#pragma unroll
  for (int i = 0; i < 16; i++) {
    const size_t idx = (size_t)(r0 + tr0 + i) * C + c0 + tc;
    tile[tr0 + i][tc] = f ? f2bf(((const float*)src)[idx]) : ((const u16*)src)[idx];
  }
  __syncthreads();
#pragma unroll
  for (int i = 0; i < 16; i++)
    dst[(size_t)(c0 + tr0 + i) * R + r0 + tc] = tile[tc][tr0 + i];
}

// ---------------------------------------------------------------------------
// C[M][N] = A[M][K] @ Bt[N][K]^T + bias[N]  (bf16 in, fp32 accum)
// ---------------------------------------------------------------------------
__global__ __launch_bounds__(256) void gemm_bt_kernel(
    const u16* __restrict__ A, const u16* __restrict__ Bt,
    const float* __restrict__ bias, void* __restrict__ C,
    int M, int N, int K, int out32) {
  __shared__ u16 As[128 * 64];
  __shared__ u16 Bs[128 * 64];
  const int tid = threadIdx.x;
  const int wave = tid >> 6, lane = tid & 63;
  const int wm = wave & 1, wn = wave >> 1;
  const int m0 = blockIdx.y * 128, n0 = blockIdx.x * 128;
  const int lr = lane >> 3, lc = lane & 7;
  const int quad = lane >> 4, l15 = lane & 15;

  float4v acc[4][4];
#pragma unroll
  for (int t = 0; t < 4; t++)
#pragma unroll
    for (int u = 0; u < 4; u++) acc[t][u] = (float4v){0.f, 0.f, 0.f, 0.f};

  for (int k0 = 0; k0 < K; k0 += 64) {
    __syncthreads();
#pragma unroll
    for (int i = 0; i < 4; i++) {
      const int brow = wave * 32 + i * 8;
      const int row = brow + lr;
      const int cG = lc ^ (row & 7);
      __builtin_amdgcn_global_load_lds(
          (gas_p)(A + (size_t)(m0 + row) * K + k0 + cG * 8),
          (las_p)(As + brow * 64), 16, 0, 0);
      __builtin_amdgcn_global_load_lds(
          (gas_p)(Bt + (size_t)(n0 + row) * K + k0 + cG * 8),
          (las_p)(Bs + brow * 64), 16, 0, 0);
    }
    __syncthreads();
#pragma unroll
    for (int ks = 0; ks < 2; ks++) {
      short8 af[4], bfr[4];
#pragma unroll
      for (int t = 0; t < 4; t++) {
        const int ar = wm * 64 + t * 16 + l15;
        af[t] = *(const short8*)(As + ar * 64 + ((ks * 4 + quad) ^ (ar & 7)) * 8);
        const int br = wn * 64 + t * 16 + l15;
        bfr[t] = *(const short8*)(Bs + br * 64 + ((ks * 4 + quad) ^ (br & 7)) * 8);
      }
#pragma unroll
      for (int t = 0; t < 4; t++)
#pragma unroll
        for (int u = 0; u < 4; u++)
          acc[t][u] = __builtin_amdgcn_mfma_f32_16x16x32_bf16(af[t], bfr[u], acc[t][u], 0, 0, 0);
    }
  }

  const int qr = quad << 2;
#pragma unroll
  for (int t = 0; t < 4; t++) {
    const int mrow = m0 + wm * 64 + t * 16 + qr;
#pragma unroll
    for (int u = 0; u < 4; u++) {
      const int col = n0 + wn * 64 + u * 16 + l15;
      const float bv = bias[col];
#pragma unroll
      for (int r = 0; r < 4; r++) {
        const float val = acc[t][u][r] + bv;
        if (out32) ((float*)C)[(size_t)(mrow + r) * N + col] = val;
        else       ((u16*)C)[(size_t)(mrow + r) * N + col] = f2bf(val);
      }
    }
  }
}

// ---------------------------------------------------------------------------
#define FA_S 2048
#define FA_D 1024
#define FA_LD 3072
#define NEG_BIG (-1e30f)

// ---------------------------------------------------------------------------
// One-shot V pre-transpose: qkv V-region [b,s,h,hd] -> vt[bh][hd][s].
// ---------------------------------------------------------------------------
__global__ __launch_bounds__(256) void vtrans_kernel(const u16* __restrict__ qkv,
                                                     u16* __restrict__ vt) {
  __shared__ __align__(16) u16 tile[64][72];
  const int tid = threadIdx.x;
  const int bh = blockIdx.y, b = bh >> 4, h = bh & 15;
  const int s0 = blockIdx.x * 64;
#pragma unroll
  for (int i = 0; i < 2; i++) {
    const int c = tid + i * 256;
    const int row = c >> 3, col = (c & 7) * 8;
    const int cs = col ^ (((row >> 3) & 7) * 8);
    *(short8*)(&tile[row][cs]) =
        *(const short8*)(qkv + (size_t)(b * FA_S + s0 + row) * FA_LD + 2 * FA_D + h * 64 + col);
  }
  __syncthreads();
#pragma unroll
  for (int i = 0; i < 2; i++) {
    const int c = tid + i * 256;
    const int hd = c >> 3, scol = (c & 7) * 8;
    const int xr = ((scol >> 3) & 7) * 8;
    __align__(16) u16 tmp[8];
#pragma unroll
    for (int j = 0; j < 8; j++) tmp[j] = tile[scol + j][hd ^ xr];
    *(short8*)(vt + (size_t)bh * (64 * FA_S) + (size_t)hd * FA_S + s0 + scol) =
        *(const short8*)tmp;
  }
}

// ---------------------------------------------------------------------------
// Per-tile softmax step (swapped-QK layout: lane owns q=l15, 16 keys).
// ---------------------------------------------------------------------------
__device__ __forceinline__ void fa_softmax(
    float4v s[4], float& m_i, float& l_i, float4v o[4],
    const float* amrow, bool diag, int wq, int quad) {
  float mcur = NEG_BIG;
  if (diag) {
#pragma unroll
    for (int nt = 0; nt < 4; nt++) {
      const float4v amv = *(const float4v*)(amrow + nt * 16 + (quad << 2));
#pragma unroll
      for (int r = 0; r < 4; r++) {
        const int kl = nt * 16 + (quad << 2) + r;
        float v = (kl <= wq) ? s[nt][r] : -10000.0f;
        v += amv[r];
        s[nt][r] = v;
        mcur = fmaxf(mcur, v);
      }
    }
  } else {
#pragma unroll
    for (int nt = 0; nt < 4; nt++) {
      const float4v amv = *(const float4v*)(amrow + nt * 16 + (quad << 2));
#pragma unroll
      for (int r = 0; r < 4; r++) {
        const float v = s[nt][r] + amv[r];
        s[nt][r] = v;
        mcur = fmaxf(mcur, v);
      }
    }
  }
  mcur = fmaxf(mcur, __shfl_xor(mcur, 16, 64));
  mcur = fmaxf(mcur, __shfl_xor(mcur, 32, 64));

  // T13 defer-max: only rescale when the max moved by >8
  if (!__all(mcur <= m_i + 8.f)) {
    const float mn = fmaxf(m_i, mcur);
    const float alpha = __expf(m_i - mn);
    m_i = mn;
    l_i *= alpha;
    float ar[4];
#pragma unroll
    for (int r = 0; r < 4; r++) ar[r] = __shfl(alpha, (quad << 2) + r, 64);
#pragma unroll
    for (int u = 0; u < 4; u++)
#pragma unroll
      for (int r = 0; r < 4; r++) o[u][r] *= ar[r];
  }

  float lsum = 0.f;
#pragma unroll
  for (int nt = 0; nt < 4; nt++)
#pragma unroll
    for (int r = 0; r < 4; r++) {
      const float e = __expf(s[nt][r] - m_i);
      s[nt][r] = e;
      lsum += e;
    }
  lsum += __shfl_xor(lsum, 16, 64);
  lsum += __shfl_xor(lsum, 32, 64);
  l_i += lsum;
}

// P -> own-wave LDS (cvt_pk + b64 writes), then O += P V (vf already in regs).
__device__ __forceinline__ void fa_pv(
    u16* Pw, const float4v s[4], const short8 vf[2][4], float4v o[4],
    int quad, int l15) {
#pragma unroll
  for (int nt = 0; nt < 4; nt++) {
    const unsigned w0 = cvt_pk_bf16(s[nt][0], s[nt][1]);
    const unsigned w1 = cvt_pk_bf16(s[nt][2], s[nt][3]);
    uint2v ww; ww.x = w0; ww.y = w1;
    *(uint2v*)(Pw + l15 * 72 + nt * 16 + (quad << 2)) = ww;
  }
  __builtin_amdgcn_s_setprio(1);
#pragma unroll
  for (int ks = 0; ks < 2; ks++) {
    const short8 pf = *(const short8*)(Pw + l15 * 72 + ks * 32 + quad * 8);
#pragma unroll
    for (int u = 0; u < 4; u++)
      o[u] = __builtin_amdgcn_mfma_f32_16x16x32_bf16(pf, vf[ks][u], o[u], 0, 0, 0);
  }
  __builtin_amdgcn_s_setprio(0);
}

// ---------------------------------------------------------------------------
// Flash attention (causal), fused pair + XCD-local grid + direct-global V.
// Round 7: REVERT the (256,4) launch bound — it squeezed VGPR to 64 and
// spilled ~110 regs of live state to scratch (WRITE_SIZE 16->585 MB, dur
// 127->325 us). Plain 256 lets the allocator pick ~116 VGPR (round-4
// verified, zero spill); LDS stays 25.6 KB so up to 4 blocks/CU resident.
// ---------------------------------------------------------------------------
__global__ __launch_bounds__(256) void flash_kernel(
    const u16* __restrict__ qkv, const u16* __restrict__ vt,
    const float* __restrict__ am, u16* __restrict__ aout) {
  __shared__ u16 Ks[2][64 * 64];   // [key][slot], slot = chunk^(key&7)
  __shared__ u16 Ps[4][16 * 72];   // per-wave P [q=l15][key] (stride 72)

  const int tid = threadIdx.x, wave = tid >> 6, lane = tid & 63;
  const int bh = blockIdx.x, b = bh >> 4, h = bh & 15;   // XCD-local: id%8=bh%8
  const int qp = blockIdx.y;                             // 0..15
  const int qtA = qp, qtB = 31 - qp;                     // qtA < qtB always
  const size_t rowbase = (size_t)b * FA_S;
  const int quad = lane >> 4, l15 = lane & 15;
  const int lr = lane >> 3, lc = lane & 7;
  const int wq = wave * 16 + l15;      // q-local within a 64-row tile
  const float* amrow0 = am + b * FA_S;
  const u16* kbase = qkv + rowbase * FA_LD + FA_D + h * 64;
  // per-lane V^T row pointers (row = u*16+l15, col base = quad*8)
  const u16* vrow[4];
#pragma unroll
  for (int u = 0; u < 4; u++)
    vrow[u] = vt + (size_t)bh * (64 * FA_S) + (size_t)(u * 16 + l15) * FA_S + quad * 8;

  // Q fragments for both tiles, pre-scaled by 1/8 (exact power of 2)
  short8 qfA[2], qfB[2];
#pragma unroll
  for (int t = 0; t < 2; t++) {
    const int qt = t ? qtB : qtA;
    const int qrow = qt * 64 + wq;
    const u16* qp_ = qkv + (rowbase + qrow) * FA_LD + h * 64 + quad * 8;
    __align__(16) u16 t0[8], t1[8];
    *(short8*)t0 = *(const short8*)qp_;
    *(short8*)t1 = *(const short8*)(qp_ + 32);
#pragma unroll
    for (int j = 0; j < 8; j++) {
      t0[j] = f2bf(bf2f(t0[j]) * 0.125f);
      t1[j] = f2bf(bf2f(t1[j]) * 0.125f);
    }
    if (t) { qfB[0] = *(const short8*)t0; qfB[1] = *(const short8*)t1; }
    else   { qfA[0] = *(const short8*)t0; qfA[1] = *(const short8*)t1; }
  }

  float mA = NEG_BIG, lA = 0.f, mB = NEG_BIG, lB = 0.f;
  float4v oA[4], oB[4];
#pragma unroll
  for (int u = 0; u < 4; u++) {
    oA[u] = (float4v){0.f, 0.f, 0.f, 0.f};
    oB[u] = (float4v){0.f, 0.f, 0.f, 0.f};
  }

  int cur = 0;
  // --- prologue: stage K tile kt=0 into buffer 0 ---
#pragma unroll
  for (int i = 0; i < 2; i++) {
    const int brow = wave * 16 + i * 8;
    const int row = brow + lr;
    const int cG = lc ^ (row & 7);
    __builtin_amdgcn_global_load_lds(
        (gas_p)(kbase + (size_t)row * FA_LD + cG * 8),
        (las_p)(Ks[0] + brow * 64), 16, 0, 0);
  }
  __syncthreads();   // drains vmcnt(0): buffer 0 ready

  for (int kt = 0; kt <= qtB; kt++) {
    // --- V fragments ks=0 direct from global (L2-hit; covered by QK+softmax)
    short8 vf[2][4];
#pragma unroll
    for (int u = 0; u < 4; u++)
      vf[0][u] = *(const short8*)(vrow[u] + kt * 64);

    // --- prefetch next K tile into Ks[cur^1] ---
    if (kt < qtB) {
#pragma unroll
      for (int i = 0; i < 2; i++) {
        const int brow = wave * 16 + i * 8;
        const int row = brow + lr;
        const int cG = lc ^ (row & 7);
        __builtin_amdgcn_global_load_lds(
            (gas_p)(kbase + (size_t)((kt + 1) * 64 + row) * FA_LD + cG * 8),
            (las_p)(Ks[cur ^ 1] + brow * 64), 16, 0, 0);
      }
    }
    const u16* Kc = Ks[cur];
    const bool actA = (kt <= qtA);   // wave-uniform

    // --- S^T = K Q^T for both tiles; each kf read feeds A and B ---
    float4v sA[4], sB[4];
#pragma unroll
    for (int nt = 0; nt < 4; nt++) {
      sA[nt] = (float4v){0.f, 0.f, 0.f, 0.f};
      sB[nt] = (float4v){0.f, 0.f, 0.f, 0.f};
    }
    __builtin_amdgcn_s_setprio(1);
#pragma unroll
    for (int ks = 0; ks < 2; ks++) {
#pragma unroll
      for (int nt = 0; nt < 4; nt++) {
        const int kr = nt * 16 + l15;
        const short8 kf = *(const short8*)(Kc + kr * 64 + (((ks * 4 + quad) ^ (kr & 7)) << 3));
        sB[nt] = __builtin_amdgcn_mfma_f32_16x16x32_bf16(kf, qfB[ks], sB[nt], 0, 0, 0);
        if (actA)
          sA[nt] = __builtin_amdgcn_mfma_f32_16x16x32_bf16(kf, qfA[ks], sA[nt], 0, 0, 0);
      }
    }
    __builtin_amdgcn_s_setprio(0);

    // --- softmax per tile ---
    const float* amrow = amrow0 + kt * 64;
    fa_softmax(sB, mB, lB, oB, amrow, kt == qtB, wq, quad);

    // --- V fragments ks=1 (covered by softmax-A before PV) ---
#pragma unroll
    for (int u = 0; u < 4; u++)
      vf[1][u] = *(const short8*)(vrow[u] + kt * 64 + 32);

    if (actA) fa_softmax(sA, mA, lA, oA, amrow, kt == qtA, wq, quad);

    u16* Pw = Ps[wave];
    fa_pv(Pw, sB, vf, oB, quad, l15);            // P_B write -> PV_B
    if (actA) fa_pv(Pw, sA, vf, oA, quad, l15);  // reuse Pw (intra-wave order)

    __syncthreads();
    cur ^= 1;
  }

  // --- epilogues ---
#pragma unroll
  for (int t = 0; t < 2; t++) {
    const float l_i = t ? lB : lA;
    const float4v* o = t ? oB : oA;
    const int qrg = (t ? qtB : qtA) * 64 + wave * 16 + quad * 4;
    float lr_[4];
#pragma unroll
    for (int r = 0; r < 4; r++) lr_[r] = __shfl(l_i, (quad << 2) + r, 64);
#pragma unroll
    for (int u = 0; u < 4; u++) {
      const int col = h * 64 + u * 16 + l15;
#pragma unroll
      for (int r = 0; r < 4; r++) {
        const float val = o[u][r] / lr_[r];
        aout[(rowbase + qrg + r) * FA_D + col] = f2bf(val);
      }
    }
  }
}

// ---------------------------------------------------------------------------
extern "C" void kernel_launch(void* const* d_in, const int* in_sizes, int n_in,
                              void* d_out, int out_size, void* d_ws, size_t ws_size,
                              hipStream_t stream) {
  (void)out_size; (void)ws_size;
  auto find = [&](int count, int def_idx) -> const void* {
    for (int i = 0; i < n_in; i++)
      if (in_sizes[i] == count) return d_in[i];
    return d_in[def_idx];
  };
  const void* x  = find(8388608, 0);
  const void* am = find(8192, 1);
  const void* Wa = find(3145728, 2);
  const void* ba = find(3072, 3);
  const void* Wp = find(1048576, 4);
  const void* bp = find(1024, 5);

  char* ws = (char*)d_ws;
  u16*   x_c  = (u16*)(ws + 0);
  u16*   Wa_t = (u16*)(ws + 16777216);
  u16*   Wp_t = (u16*)(ws + 23068672);
  u16*   qkv  = (u16*)(ws + 25165824);
  u16*   abuf = (u16*)(ws + 75497472);
  float* ba_f = (float*)(ws + 92274688);
  float* bp_f = (float*)(ws + 92286976);
  float* am_f = (float*)(ws + 92291072);
  int*   flag = (int*)(ws + 92323840);
  // V^T reuses the x_c region (dead after the first GEMM, stream-ordered).
  u16*   vt   = (u16*)(ws + 0);

  const int M = 8192, D = 1024;

  detect_kernel<<<1, 256, 0, stream>>>((const u16*)x, flag);
  cvt_bf16_kernel<<<2048, 256, 0, stream>>>(x, flag, x_c, M * D);
  cvt_f32_kernel<<<12, 256, 0, stream>>>(ba, flag, ba_f, 3072);
  cvt_f32_kernel<<<4, 256, 0, stream>>>(bp, flag, bp_f, 1024);
  cvt_f32_kernel<<<32, 256, 0, stream>>>(am, flag, am_f, 4 * FA_S);
  cvt_transpose_kernel<<<dim3(3072 / 64, 1024 / 64), 256, 0, stream>>>(Wa, flag, Wa_t, 1024, 3072);
  cvt_transpose_kernel<<<dim3(1024 / 64, 1024 / 64), 256, 0, stream>>>(Wp, flag, Wp_t, 1024, 1024);

  gemm_bt_kernel<<<dim3(3072 / 128, M / 128), 256, 0, stream>>>(
      x_c, Wa_t, ba_f, qkv, M, 3072, D, 0);
  vtrans_kernel<<<dim3(FA_S / 64, 64), 256, 0, stream>>>(qkv, vt);
  // grid x=bh (64), y=qp (16): wg id % 8 == bh % 8 -> per-bh XCD locality
  flash_kernel<<<dim3(64, 16), 256, 0, stream>>>(qkv, vt, am_f, abuf);
  gemm_bt_kernel<<<dim3(D / 128, M / 128), 256, 0, stream>>>(
      abuf, Wp_t, bp_f, d_out, M, D, D, 1);
}

// Round 8
// 349.282 us; speedup vs baseline: 1.5886x; 1.2958x over previous
//
#include <hip/hip_runtime.h>
#include <stdint.h>
#include <stddef.h>

typedef unsigned short u16;
typedef __attribute__((ext_vector_type(8))) short short8;   // 8 x bf16 MFMA A/B frag
typedef __attribute__((ext_vector_type(4))) float float4v;  // MFMA C/D frag
typedef __attribute__((ext_vector_type(2))) unsigned uint2v;

typedef const __attribute__((address_space(1))) void* gas_p;
typedef __attribute__((address_space(3))) void* las_p;

__device__ __forceinline__ float bf2f(u16 h) {
  union { unsigned u; float f; } v; v.u = ((unsigned)h) << 16; return v.f;
}
__device__ __forceinline__ u16 f2bf(float f) {
  union { float f; unsigned u; } v; v.f = f;
  return (u16)((v.u + 0x7FFFu + ((v.u >> 16) & 1u)) >> 16);
}
// packed f32->bf16 (RNE), gfx950. No builtin exists (m240); inline asm.
__device__ __forceinline__ unsigned cvt_pk_bf16(float lo, float hi) {
  unsigned r;
  asm("v_cvt_pk_bf16_f32 %0, %1, %2" : "=v"(r) : "v"(lo), "v"(hi));
  return r;
}

// ---------------------------------------------------------------------------
__global__ __launch_bounds__(256) void detect_kernel(const u16* __restrict__ src,
                                                     int* __restrict__ flag) {
  __shared__ int cnt[256];
  int c = 0;
  for (int j = 0; j < 256; j++) {
    const u16 w = src[threadIdx.x + j * 256];
    c += (((w >> 7) & 0xFF) == 0xFF) ? 1 : 0;
  }
  cnt[threadIdx.x] = c;
  __syncthreads();
  if (threadIdx.x == 0) {
    int t = 0;
    for (int i = 0; i < 256; i++) t += cnt[i];
    *flag = (t > 0) ? 1 : 0;
  }
}

__global__ __launch_bounds__(256) void cvt_bf16_kernel(const void* __restrict__ src,
                                                       const int* __restrict__ flag,
                                                       u16* __restrict__ dst, int n) {
  const int f = *flag;
  const int stride = gridDim.x * 256;
  for (int i = blockIdx.x * 256 + threadIdx.x; i < n; i += stride)
    dst[i] = f ? f2bf(((const float*)src)[i]) : ((const u16*)src)[i];
}

__global__ __launch_bounds__(256) void cvt_f32_kernel(const void* __restrict__ src,
                                                      const int* __restrict__ flag,
                                                      float* __restrict__ dst, int n) {
  const int f = *flag;
  const int stride = gridDim.x * 256;
  for (int i = blockIdx.x * 256 + threadIdx.x; i < n; i += stride)
    dst[i] = f ? ((const float*)src)[i] : bf2f(((const u16*)src)[i]);
}

__global__ __launch_bounds__(256) void cvt_transpose_kernel(
    const void* __restrict__ src, const int* __restrict__ flag,
    u16* __restrict__ dst, int R, int C) {
  __shared__ u16 tile[64][65];
  const int f = *flag;
  const int c0 = blockIdx.x * 64, r0 = blockIdx.y * 64;
  const int tc = threadIdx.x & 63;
  const int tr0 = (threadIdx.x >> 6) * 16;
#pragma unroll
  for (int i = 0; i < 16; i++) {
    const size_t idx = (size_t)(r0 + tr0 + i) * C + c0 + tc;
    tile[tr0 + i][tc] = f ? f2bf(((const float*)src)[idx]) : ((const u16*)src)[idx];
  }
  __syncthreads();
#pragma unroll
  for (int i = 0; i < 16; i++)
    dst[(size_t)(c0 + tr0 + i) * R + r0 + tc] = tile[tc][tr0 + i];
}

// ---------------------------------------------------------------------------
// C[M][N] = A[M][K] @ Bt[N][K]^T + bias[N]  (bf16 in, fp32 accum)
// ---------------------------------------------------------------------------
__global__ __launch_bounds__(256) void gemm_bt_kernel(
    const u16* __restrict__ A, const u16* __restrict__ Bt,
    const float* __restrict__ bias, void* __restrict__ C,
    int M, int N, int K, int out32) {
  __shared__ u16 As[128 * 64];
  __shared__ u16 Bs[128 * 64];
  const int tid = threadIdx.x;
  const int wave = tid >> 6, lane = tid & 63;
  const int wm = wave & 1, wn = wave >> 1;
  const int m0 = blockIdx.y * 128, n0 = blockIdx.x * 128;
  const int lr = lane >> 3, lc = lane & 7;
  const int quad = lane >> 4, l15 = lane & 15;

  float4v acc[4][4];
#pragma unroll
  for (int t = 0; t < 4; t++)
#pragma unroll
    for (int u = 0; u < 4; u++) acc[t][u] = (float4v){0.f, 0.f, 0.f, 0.f};

  for (int k0 = 0; k0 < K; k0 += 64) {
    __syncthreads();
#pragma unroll
    for (int i = 0; i < 4; i++) {
      const int brow = wave * 32 + i * 8;
      const int row = brow + lr;
      const int cG = lc ^ (row & 7);
      __builtin_amdgcn_global_load_lds(
          (gas_p)(A + (size_t)(m0 + row) * K + k0 + cG * 8),
          (las_p)(As + brow * 64), 16, 0, 0);
      __builtin_amdgcn_global_load_lds(
          (gas_p)(Bt + (size_t)(n0 + row) * K + k0 + cG * 8),
          (las_p)(Bs + brow * 64), 16, 0, 0);
    }
    __syncthreads();
#pragma unroll
    for (int ks = 0; ks < 2; ks++) {
      short8 af[4], bfr[4];
#pragma unroll
      for (int t = 0; t < 4; t++) {
        const int ar = wm * 64 + t * 16 + l15;
        af[t] = *(const short8*)(As + ar * 64 + ((ks * 4 + quad) ^ (ar & 7)) * 8);
        const int br = wn * 64 + t * 16 + l15;
        bfr[t] = *(const short8*)(Bs + br * 64 + ((ks * 4 + quad) ^ (br & 7)) * 8);
      }
#pragma unroll
      for (int t = 0; t < 4; t++)
#pragma unroll
        for (int u = 0; u < 4; u++)
          acc[t][u] = __builtin_amdgcn_mfma_f32_16x16x32_bf16(af[t], bfr[u], acc[t][u], 0, 0, 0);
    }
  }

  const int qr = quad << 2;
#pragma unroll
  for (int t = 0; t < 4; t++) {
    const int mrow = m0 + wm * 64 + t * 16 + qr;
#pragma unroll
    for (int u = 0; u < 4; u++) {
      const int col = n0 + wn * 64 + u * 16 + l15;
      const float bv = bias[col];
#pragma unroll
      for (int r = 0; r < 4; r++) {
        const float val = acc[t][u][r] + bv;
        if (out32) ((float*)C)[(size_t)(mrow + r) * N + col] = val;
        else       ((u16*)C)[(size_t)(mrow + r) * N + col] = f2bf(val);
      }
    }
  }
}

// ---------------------------------------------------------------------------
#define FA_S 2048
#define FA_D 1024
#define FA_LD 3072
#define NEG_BIG (-1e30f)

// ---------------------------------------------------------------------------
// One-shot V pre-transpose: qkv V-region [b,s,h,hd] -> vt[bh][hd][s].
// ---------------------------------------------------------------------------
__global__ __launch_bounds__(256) void vtrans_kernel(const u16* __restrict__ qkv,
                                                     u16* __restrict__ vt) {
  __shared__ __align__(16) u16 tile[64][72];
  const int tid = threadIdx.x;
  const int bh = blockIdx.y, b = bh >> 4, h = bh & 15;
  const int s0 = blockIdx.x * 64;
#pragma unroll
  for (int i = 0; i < 2; i++) {
    const int c = tid + i * 256;
    const int row = c >> 3, col = (c & 7) * 8;
    const int cs = col ^ (((row >> 3) & 7) * 8);
    *(short8*)(&tile[row][cs]) =
        *(const short8*)(qkv + (size_t)(b * FA_S + s0 + row) * FA_LD + 2 * FA_D + h * 64 + col);
  }
  __syncthreads();
#pragma unroll
  for (int i = 0; i < 2; i++) {
    const int c = tid + i * 256;
    const int hd = c >> 3, scol = (c & 7) * 8;
    const int xr = ((scol >> 3) & 7) * 8;
    __align__(16) u16 tmp[8];
#pragma unroll
    for (int j = 0; j < 8; j++) tmp[j] = tile[scol + j][hd ^ xr];
    *(short8*)(vt + (size_t)bh * (64 * FA_S) + (size_t)hd * FA_S + s0 + scol) =
        *(const short8*)tmp;
  }
}

// ---------------------------------------------------------------------------
// Per-tile softmax step (swapped-QK layout: lane owns q=l15, 16 keys).
// Tree-shaped max/sum: dependent chain depth 4 instead of 16.
// ---------------------------------------------------------------------------
__device__ __forceinline__ void fa_softmax(
    float4v s[4], float& m_i, float& l_i, float4v o[4],
    const float* amrow, bool diag, int wq, int quad) {
  if (diag) {
#pragma unroll
    for (int nt = 0; nt < 4; nt++) {
      const float4v amv = *(const float4v*)(amrow + nt * 16 + (quad << 2));
#pragma unroll
      for (int r = 0; r < 4; r++) {
        const int kl = nt * 16 + (quad << 2) + r;
        float v = (kl <= wq) ? s[nt][r] : -10000.0f;
        s[nt][r] = v + amv[r];
      }
    }
  } else {
#pragma unroll
    for (int nt = 0; nt < 4; nt++) {
      const float4v amv = *(const float4v*)(amrow + nt * 16 + (quad << 2));
#pragma unroll
      for (int r = 0; r < 4; r++)
        s[nt][r] = s[nt][r] + amv[r];
    }
  }
  // tree max over 16 in-lane values (depth 4)
  float mnt[4];
#pragma unroll
  for (int nt = 0; nt < 4; nt++)
    mnt[nt] = fmaxf(fmaxf(s[nt][0], s[nt][1]), fmaxf(s[nt][2], s[nt][3]));
  float mcur = fmaxf(fmaxf(mnt[0], mnt[1]), fmaxf(mnt[2], mnt[3]));
  mcur = fmaxf(mcur, __shfl_xor(mcur, 16, 64));
  mcur = fmaxf(mcur, __shfl_xor(mcur, 32, 64));

  // T13 defer-max: only rescale when the max moved by >8
  if (!__all(mcur <= m_i + 8.f)) {
    const float mn = fmaxf(m_i, mcur);
    const float alpha = __expf(m_i - mn);
    m_i = mn;
    l_i *= alpha;
    float ar[4];
#pragma unroll
    for (int r = 0; r < 4; r++) ar[r] = __shfl(alpha, (quad << 2) + r, 64);
#pragma unroll
    for (int u = 0; u < 4; u++)
#pragma unroll
      for (int r = 0; r < 4; r++) o[u][r] *= ar[r];
  }

  // exp + tree sum (depth 4)
  float lnt[4];
#pragma unroll
  for (int nt = 0; nt < 4; nt++) {
#pragma unroll
    for (int r = 0; r < 4; r++)
      s[nt][r] = __expf(s[nt][r] - m_i);
    lnt[nt] = (s[nt][0] + s[nt][1]) + (s[nt][2] + s[nt][3]);
  }
  float lsum = (lnt[0] + lnt[1]) + (lnt[2] + lnt[3]);
  lsum += __shfl_xor(lsum, 16, 64);
  lsum += __shfl_xor(lsum, 32, 64);
  l_i += lsum;
}

// P -> own-wave LDS (cvt_pk + b64 writes), then O += P V (vf already in regs).
__device__ __forceinline__ void fa_pv(
    u16* Pw, const float4v s[4], const short8 vf[2][4], float4v o[4],
    int quad, int l15) {
#pragma unroll
  for (int nt = 0; nt < 4; nt++) {
    const unsigned w0 = cvt_pk_bf16(s[nt][0], s[nt][1]);
    const unsigned w1 = cvt_pk_bf16(s[nt][2], s[nt][3]);
    uint2v ww; ww.x = w0; ww.y = w1;
    *(uint2v*)(Pw + l15 * 72 + nt * 16 + (quad << 2)) = ww;
  }
  __builtin_amdgcn_s_setprio(1);
#pragma unroll
  for (int ks = 0; ks < 2; ks++) {
    const short8 pf = *(const short8*)(Pw + l15 * 72 + ks * 32 + quad * 8);
#pragma unroll
    for (int u = 0; u < 4; u++)
      o[u] = __builtin_amdgcn_mfma_f32_16x16x32_bf16(pf, vf[ks][u], o[u], 0, 0, 0);
  }
  __builtin_amdgcn_s_setprio(0);
}

// ---------------------------------------------------------------------------
// Flash attention (causal), fused pair + XCD-local grid (round 4 base) +
// SINGLE-BUFFERED V (round 8): V tile for the CURRENT kt stages at iteration
// top; the mid-iteration __syncthreads (drains vmcnt per HIP semantics)
// makes Vs ready exactly before PV, with QK+softmax-B (~500cy) covering the
// load latency. K keeps its double-buffered prefetch. LDS 41984 -> 33280 B
// => 4 blocks/CU resident (was 3): 4 mutually-independent waves/SIMD hide
// each other's serial softmax chains. Direct-global V (r5-7) is abandoned:
// scattered vf loads serialize the vmem pipe (224us, r7 post-mortem).
// ---------------------------------------------------------------------------
__global__ __launch_bounds__(256) void flash_kernel(
    const u16* __restrict__ qkv, const u16* __restrict__ vt,
    const float* __restrict__ am, u16* __restrict__ aout) {
  __shared__ u16 Ks[2][64 * 64];   // [key][slot], slot = chunk^(key&7), dbuf
  __shared__ u16 Vs[64 * 64];      // [hd][slot],  slot = chunk^(hd&7), single
  __shared__ u16 Ps[4][16 * 72];   // per-wave P [q=l15][key] (stride 72)

  const int tid = threadIdx.x, wave = tid >> 6, lane = tid & 63;
  const int bh = blockIdx.x, b = bh >> 4, h = bh & 15;   // XCD-local: id%8=bh%8
  const int qp = blockIdx.y;                             // 0..15
  const int qtA = qp, qtB = 31 - qp;                     // qtA < qtB always
  const size_t rowbase = (size_t)b * FA_S;
  const int quad = lane >> 4, l15 = lane & 15;
  const int lr = lane >> 3, lc = lane & 7;
  const int wq = wave * 16 + l15;      // q-local within a 64-row tile
  const float* amrow0 = am + b * FA_S;
  const u16* kbase = qkv + rowbase * FA_LD + FA_D + h * 64;
  const u16* vbase = vt + (size_t)bh * (64 * FA_S);

  // Q fragments for both tiles, pre-scaled by 1/8 (exact power of 2)
  short8 qfA[2], qfB[2];
#pragma unroll
  for (int t = 0; t < 2; t++) {
    const int qt = t ? qtB : qtA;
    const int qrow = qt * 64 + wq;
    const u16* qp_ = qkv + (rowbase + qrow) * FA_LD + h * 64 + quad * 8;
    __align__(16) u16 t0[8], t1[8];
    *(short8*)t0 = *(const short8*)qp_;
    *(short8*)t1 = *(const short8*)(qp_ + 32);
#pragma unroll
    for (int j = 0; j < 8; j++) {
      t0[j] = f2bf(bf2f(t0[j]) * 0.125f);
      t1[j] = f2bf(bf2f(t1[j]) * 0.125f);
    }
    if (t) { qfB[0] = *(const short8*)t0; qfB[1] = *(const short8*)t1; }
    else   { qfA[0] = *(const short8*)t0; qfA[1] = *(const short8*)t1; }
  }

  float mA = NEG_BIG, lA = 0.f, mB = NEG_BIG, lB = 0.f;
  float4v oA[4], oB[4];
#pragma unroll
  for (int u = 0; u < 4; u++) {
    oA[u] = (float4v){0.f, 0.f, 0.f, 0.f};
    oB[u] = (float4v){0.f, 0.f, 0.f, 0.f};
  }

  int cur = 0;
  // --- prologue: stage K tile kt=0 into buffer 0 ---
#pragma unroll
  for (int i = 0; i < 2; i++) {
    const int brow = wave * 16 + i * 8;
    const int row = brow + lr;
    const int cG = lc ^ (row & 7);
    __builtin_amdgcn_global_load_lds(
        (gas_p)(kbase + (size_t)row * FA_LD + cG * 8),
        (las_p)(Ks[0] + brow * 64), 16, 0, 0);
  }
  __syncthreads();   // drains vmcnt(0): K buffer 0 ready

  for (int kt = 0; kt <= qtB; kt++) {
    // --- stage V(kt) into the single buffer (Vs free: end barrier of kt-1)
#pragma unroll
    for (int i = 0; i < 2; i++) {
      const int brow = wave * 16 + i * 8;
      const int row = brow + lr;
      const int cG = lc ^ (row & 7);
      __builtin_amdgcn_global_load_lds(
          (gas_p)(vbase + (size_t)row * FA_S + kt * 64 + cG * 8),
          (las_p)(Vs + brow * 64), 16, 0, 0);
    }
    // --- prefetch next K tile into Ks[cur^1] ---
    if (kt < qtB) {
#pragma unroll
      for (int i = 0; i < 2; i++) {
        const int brow = wave * 16 + i * 8;
        const int row = brow + lr;
        const int cG = lc ^ (row & 7);
        __builtin_amdgcn_global_load_lds(
            (gas_p)(kbase + (size_t)((kt + 1) * 64 + row) * FA_LD + cG * 8),
            (las_p)(Ks[cur ^ 1] + brow * 64), 16, 0, 0);
      }
    }
    const u16* Kc = Ks[cur];
    const bool actA = (kt <= qtA);   // wave-uniform

    // --- S^T = K Q^T for both tiles; each kf read feeds A and B ---
    float4v sA[4], sB[4];
#pragma unroll
    for (int nt = 0; nt < 4; nt++) {
      sA[nt] = (float4v){0.f, 0.f, 0.f, 0.f};
      sB[nt] = (float4v){0.f, 0.f, 0.f, 0.f};
    }
    __builtin_amdgcn_s_setprio(1);
#pragma unroll
    for (int ks = 0; ks < 2; ks++) {
#pragma unroll
      for (int nt = 0; nt < 4; nt++) {
        const int kr = nt * 16 + l15;
        const short8 kf = *(const short8*)(Kc + kr * 64 + (((ks * 4 + quad) ^ (kr & 7)) << 3));
        sB[nt] = __builtin_amdgcn_mfma_f32_16x16x32_bf16(kf, qfB[ks], sB[nt], 0, 0, 0);
        if (actA)
          sA[nt] = __builtin_amdgcn_mfma_f32_16x16x32_bf16(kf, qfA[ks], sA[nt], 0, 0, 0);
      }
    }
    __builtin_amdgcn_s_setprio(0);

    // --- softmax B (covers V/K load latency) ---
    const float* amrow = amrow0 + kt * 64;
    fa_softmax(sB, mB, lB, oB, amrow, kt == qtB, wq, quad);

    __syncthreads();   // drains vmcnt: Vs (and next-K) landed, all waves

    // --- V fragments from LDS, shared by both PV steps ---
    short8 vf[2][4];
#pragma unroll
    for (int ks = 0; ks < 2; ks++)
#pragma unroll
      for (int u = 0; u < 4; u++) {
        const int n = u * 16 + l15;
        vf[ks][u] = *(const short8*)(Vs + n * 64 + (((ks * 4 + quad) ^ (n & 7)) << 3));
      }

    if (actA) fa_softmax(sA, mA, lA, oA, amrow, kt == qtA, wq, quad);

    u16* Pw = Ps[wave];
    fa_pv(Pw, sB, vf, oB, quad, l15);            // P_B write -> PV_B
    if (actA) fa_pv(Pw, sA, vf, oA, quad, l15);  // reuse Pw (intra-wave order)

    __syncthreads();   // all waves done reading Vs & Ks[cur]
    cur ^= 1;
  }

  // --- epilogues ---
#pragma unroll
  for (int t = 0; t < 2; t++) {
    const float l_i = t ? lB : lA;
    const float4v* o = t ? oB : oA;
    const int qrg = (t ? qtB : qtA) * 64 + wave * 16 + quad * 4;
    float lr_[4];
#pragma unroll
    for (int r = 0; r < 4; r++) lr_[r] = __shfl(l_i, (quad << 2) + r, 64);
#pragma unroll
    for (int u = 0; u < 4; u++) {
      const int col = h * 64 + u * 16 + l15;
#pragma unroll
      for (int r = 0; r < 4; r++) {
        const float val = o[u][r] / lr_[r];
        aout[(rowbase + qrg + r) * FA_D + col] = f2bf(val);
      }
    }
  }
}

// ---------------------------------------------------------------------------
extern "C" void kernel_launch(void* const* d_in, const int* in_sizes, int n_in,
                              void* d_out, int out_size, void* d_ws, size_t ws_size,
                              hipStream_t stream) {
  (void)out_size; (void)ws_size;
  auto find = [&](int count, int def_idx) -> const void* {
    for (int i = 0; i < n_in; i++)
      if (in_sizes[i] == count) return d_in[i];
    return d_in[def_idx];
  };
  const void* x  = find(8388608, 0);
  const void* am = find(8192, 1);
  const void* Wa = find(3145728, 2);
  const void* ba = find(3072, 3);
  const void* Wp = find(1048576, 4);
  const void* bp = find(1024, 5);

  char* ws = (char*)d_ws;
  u16*   x_c  = (u16*)(ws + 0);
  u16*   Wa_t = (u16*)(ws + 16777216);
  u16*   Wp_t = (u16*)(ws + 23068672);
  u16*   qkv  = (u16*)(ws + 25165824);
  u16*   abuf = (u16*)(ws + 75497472);
  float* ba_f = (float*)(ws + 92274688);
  float* bp_f = (float*)(ws + 92286976);
  float* am_f = (float*)(ws + 92291072);
  int*   flag = (int*)(ws + 92323840);
  // V^T reuses the x_c region (dead after the first GEMM, stream-ordered).
  u16*   vt   = (u16*)(ws + 0);

  const int M = 8192, D = 1024;

  detect_kernel<<<1, 256, 0, stream>>>((const u16*)x, flag);
  cvt_bf16_kernel<<<2048, 256, 0, stream>>>(x, flag, x_c, M * D);
  cvt_f32_kernel<<<12, 256, 0, stream>>>(ba, flag, ba_f, 3072);
  cvt_f32_kernel<<<4, 256, 0, stream>>>(bp, flag, bp_f, 1024);
  cvt_f32_kernel<<<32, 256, 0, stream>>>(am, flag, am_f, 4 * FA_S);
  cvt_transpose_kernel<<<dim3(3072 / 64, 1024 / 64), 256, 0, stream>>>(Wa, flag, Wa_t, 1024, 3072);
  cvt_transpose_kernel<<<dim3(1024 / 64, 1024 / 64), 256, 0, stream>>>(Wp, flag, Wp_t, 1024, 1024);

  gemm_bt_kernel<<<dim3(3072 / 128, M / 128), 256, 0, stream>>>(
      x_c, Wa_t, ba_f, qkv, M, 3072, D, 0);
  vtrans_kernel<<<dim3(FA_S / 64, 64), 256, 0, stream>>>(qkv, vt);
  // grid x=bh (64), y=qp (16): wg id % 8 == bh % 8 -> per-bh XCD locality
  flash_kernel<<<dim3(64, 16), 256, 0, stream>>>(qkv, vt, am_f, abuf);
  gemm_bt_kernel<<<dim3(D / 128, M / 128), 256, 0, stream>>>(
      abuf, Wp_t, bp_f, d_out, M, D, D, 1);
}

// Round 9
// 343.331 us; speedup vs baseline: 1.6161x; 1.0173x over previous
//
#include <hip/hip_runtime.h>
#include <stdint.h>
#include <stddef.h>

typedef unsigned short u16;
typedef __attribute__((ext_vector_type(8))) short short8;   // 8 x bf16 MFMA A/B frag
typedef __attribute__((ext_vector_type(4))) short short4v;  // 4 x bf16 (8B store)
typedef __attribute__((ext_vector_type(4))) float float4v;  // MFMA C/D frag
typedef __attribute__((ext_vector_type(2))) unsigned uint2v;

typedef const __attribute__((address_space(1))) void* gas_p;
typedef __attribute__((address_space(3))) void* las_p;

#define L2E 1.4426950408889634f
#define NMASK (-14426.950408889634f)   // -10000 * log2(e)

__device__ __forceinline__ float bf2f(u16 h) {
  union { unsigned u; float f; } v; v.u = ((unsigned)h) << 16; return v.f;
}
__device__ __forceinline__ u16 f2bf(float f) {
  union { float f; unsigned u; } v; v.f = f;
  return (u16)((v.u + 0x7FFFu + ((v.u >> 16) & 1u)) >> 16);
}
// packed f32->bf16 (RNE), gfx950. No builtin exists; inline asm.
__device__ __forceinline__ unsigned cvt_pk_bf16(float lo, float hi) {
  unsigned r;
  asm("v_cvt_pk_bf16_f32 %0, %1, %2" : "=v"(r) : "v"(lo), "v"(hi));
  return r;
}
// raw v_exp_f32 (2^x) and v_rcp_f32 — avoid ocml wrapper muls/fixups.
__device__ __forceinline__ float exp2v(float x) {
  float r; asm("v_exp_f32 %0, %1" : "=v"(r) : "v"(x)); return r;
}
__device__ __forceinline__ float rcpv(float x) {
  float r; asm("v_rcp_f32 %0, %1" : "=v"(r) : "v"(x)); return r;
}

// ---------------------------------------------------------------------------
__global__ __launch_bounds__(256) void detect_kernel(const u16* __restrict__ src,
                                                     int* __restrict__ flag) {
  __shared__ int cnt[256];
  int c = 0;
  for (int j = 0; j < 256; j++) {
    const u16 w = src[threadIdx.x + j * 256];
    c += (((w >> 7) & 0xFF) == 0xFF) ? 1 : 0;
  }
  cnt[threadIdx.x] = c;
  __syncthreads();
  if (threadIdx.x == 0) {
    int t = 0;
    for (int i = 0; i < 256; i++) t += cnt[i];
    *flag = (t > 0) ? 1 : 0;
  }
}

__global__ __launch_bounds__(256) void cvt_bf16_kernel(const void* __restrict__ src,
                                                       const int* __restrict__ flag,
                                                       u16* __restrict__ dst, int n) {
  const int f = *flag;
  const int stride = gridDim.x * 256;
  for (int i = blockIdx.x * 256 + threadIdx.x; i < n; i += stride)
    dst[i] = f ? f2bf(((const float*)src)[i]) : ((const u16*)src)[i];
}

__global__ __launch_bounds__(256) void cvt_f32_kernel(const void* __restrict__ src,
                                                      const int* __restrict__ flag,
                                                      float* __restrict__ dst, int n,
                                                      float scale) {
  const int f = *flag;
  const int stride = gridDim.x * 256;
  for (int i = blockIdx.x * 256 + threadIdx.x; i < n; i += stride) {
    const float v = f ? ((const float*)src)[i] : bf2f(((const u16*)src)[i]);
    dst[i] = v * scale;
  }
}

__global__ __launch_bounds__(256) void cvt_transpose_kernel(
    const void* __restrict__ src, const int* __restrict__ flag,
    u16* __restrict__ dst, int R, int C) {
  __shared__ u16 tile[64][65];
  const int f = *flag;
  const int c0 = blockIdx.x * 64, r0 = blockIdx.y * 64;
  const int tc = threadIdx.x & 63;
  const int tr0 = (threadIdx.x >> 6) * 16;
#pragma unroll
  for (int i = 0; i < 16; i++) {
    const size_t idx = (size_t)(r0 + tr0 + i) * C + c0 + tc;
    tile[tr0 + i][tc] = f ? f2bf(((const float*)src)[idx]) : ((const u16*)src)[idx];
  }
  __syncthreads();
#pragma unroll
  for (int i = 0; i < 16; i++)
    dst[(size_t)(c0 + tr0 + i) * R + r0 + tc] = tile[tc][tr0 + i];
}

// ---------------------------------------------------------------------------
// C[M][N] = A[M][K] @ Bt[N][K]^T + bias[N]  (bf16 in, fp32 accum)
// vfuse: for col>=2048 (the V-third of qkv), write TRANSPOSED into the same
// region with the permuted layout slice(bh,hd) -> rows 2*(bh*64+hd)+(s>>10),
// offset 2048+(s&1023). Replaces the separate vtrans kernel (no extra ws,
// no race: x_c untouched). Blocks are column-uniform (2048 % 128 == 0).
// ---------------------------------------------------------------------------
__global__ __launch_bounds__(256) void gemm_bt_kernel(
    const u16* __restrict__ A, const u16* __restrict__ Bt,
    const float* __restrict__ bias, void* __restrict__ C,
    int M, int N, int K, int out32, int vfuse) {
  __shared__ u16 As[128 * 64];
  __shared__ u16 Bs[128 * 64];
  const int tid = threadIdx.x;
  const int wave = tid >> 6, lane = tid & 63;
  const int wm = wave & 1, wn = wave >> 1;
  const int m0 = blockIdx.y * 128, n0 = blockIdx.x * 128;
  const int lr = lane >> 3, lc = lane & 7;
  const int quad = lane >> 4, l15 = lane & 15;

  float4v acc[4][4];
#pragma unroll
  for (int t = 0; t < 4; t++)
#pragma unroll
    for (int u = 0; u < 4; u++) acc[t][u] = (float4v){0.f, 0.f, 0.f, 0.f};

  for (int k0 = 0; k0 < K; k0 += 64) {
    __syncthreads();
#pragma unroll
    for (int i = 0; i < 4; i++) {
      const int brow = wave * 32 + i * 8;
      const int row = brow + lr;
      const int cG = lc ^ (row & 7);
      __builtin_amdgcn_global_load_lds(
          (gas_p)(A + (size_t)(m0 + row) * K + k0 + cG * 8),
          (las_p)(As + brow * 64), 16, 0, 0);
      __builtin_amdgcn_global_load_lds(
          (gas_p)(Bt + (size_t)(n0 + row) * K + k0 + cG * 8),
          (las_p)(Bs + brow * 64), 16, 0, 0);
    }
    __syncthreads();
#pragma unroll
    for (int ks = 0; ks < 2; ks++) {
      short8 af[4], bfr[4];
#pragma unroll
      for (int t = 0; t < 4; t++) {
        const int ar = wm * 64 + t * 16 + l15;
        af[t] = *(const short8*)(As + ar * 64 + ((ks * 4 + quad) ^ (ar & 7)) * 8);
        const int br = wn * 64 + t * 16 + l15;
        bfr[t] = *(const short8*)(Bs + br * 64 + ((ks * 4 + quad) ^ (br & 7)) * 8);
      }
#pragma unroll
      for (int t = 0; t < 4; t++)
#pragma unroll
        for (int u = 0; u < 4; u++)
          acc[t][u] = __builtin_amdgcn_mfma_f32_16x16x32_bf16(af[t], bfr[u], acc[t][u], 0, 0, 0);
    }
  }

  const int qr = quad << 2;
  if (vfuse && n0 >= 2048) {
    // V-columns: transposed permuted write into the V-third of C (= qkv)
    const int b = m0 >> 11;   // uniform per block (2048 % 128 == 0)
#pragma unroll
    for (int t = 0; t < 4; t++) {
      const int mrow = m0 + wm * 64 + t * 16 + qr;
      const int s0 = mrow & 2047;           // +r are consecutive, same 1K half
#pragma unroll
      for (int u = 0; u < 4; u++) {
        const int col = n0 + wn * 64 + u * 16 + l15;
        const int hdcol = col - 2048;
        const int h = hdcol >> 6, hd = hdcol & 63;
        const float bv = bias[col];
        __align__(8) u16 pk[4];
#pragma unroll
        for (int r = 0; r < 4; r++) pk[r] = f2bf(acc[t][u][r] + bv);
        const int rowq = 2 * ((b * 16 + h) * 64 + hd) + (s0 >> 10);
        u16* dst = (u16*)C + (size_t)rowq * 3072 + 2048 + (s0 & 1023);
        *(short4v*)dst = *(const short4v*)pk;
      }
    }
    return;
  }
#pragma unroll
  for (int t = 0; t < 4; t++) {
    const int mrow = m0 + wm * 64 + t * 16 + qr;
#pragma unroll
    for (int u = 0; u < 4; u++) {
      const int col = n0 + wn * 64 + u * 16 + l15;
      const float bv = bias[col];
#pragma unroll
      for (int r = 0; r < 4; r++) {
        const float val = acc[t][u][r] + bv;
        if (out32) ((float*)C)[(size_t)(mrow + r) * N + col] = val;
        else       ((u16*)C)[(size_t)(mrow + r) * N + col] = f2bf(val);
      }
    }
  }
}

// ---------------------------------------------------------------------------
#define FA_S 2048
#define FA_D 1024
#define FA_LD 3072
#define NEG_BIG (-1e30f)

// ---------------------------------------------------------------------------
// Per-tile softmax step, exp2 (log2e) domain: s' = fma(s, L2E, am'),
// am' pre-scaled by log2e; masked entries = am' - 14427. exp via raw
// v_exp_f32 (2^x) — saves the hidden v_mul of __expf per element.
// l/m keep identical semantics (s'-m' == (s-m)*log2e).
// ---------------------------------------------------------------------------
__device__ __forceinline__ void fa_softmax(
    float4v s[4], float& m_i, float& l_i, float4v o[4],
    const float* amrow, bool diag, int wq, int quad) {
  if (diag) {
#pragma unroll
    for (int nt = 0; nt < 4; nt++) {
      const float4v amv = *(const float4v*)(amrow + nt * 16 + (quad << 2));
#pragma unroll
      for (int r = 0; r < 4; r++) {
        const int kl = nt * 16 + (quad << 2) + r;
        s[nt][r] = (kl <= wq) ? fmaf(s[nt][r], L2E, amv[r]) : (amv[r] + NMASK);
      }
    }
  } else {
#pragma unroll
    for (int nt = 0; nt < 4; nt++) {
      const float4v amv = *(const float4v*)(amrow + nt * 16 + (quad << 2));
#pragma unroll
      for (int r = 0; r < 4; r++)
        s[nt][r] = fmaf(s[nt][r], L2E, amv[r]);
    }
  }
  // tree max over 16 in-lane values (depth 4)
  float mnt[4];
#pragma unroll
  for (int nt = 0; nt < 4; nt++)
    mnt[nt] = fmaxf(fmaxf(s[nt][0], s[nt][1]), fmaxf(s[nt][2], s[nt][3]));
  float mcur = fmaxf(fmaxf(mnt[0], mnt[1]), fmaxf(mnt[2], mnt[3]));
  mcur = fmaxf(mcur, __shfl_xor(mcur, 16, 64));
  mcur = fmaxf(mcur, __shfl_xor(mcur, 32, 64));

  // T13 defer-max (log2 domain: 11.54 == 8 nats; P bounded by 2^11.5, bf16-safe)
  if (!__all(mcur <= m_i + 11.5416f)) {
    const float mn = fmaxf(m_i, mcur);
    const float alpha = exp2v(m_i - mn);
    m_i = mn;
    l_i *= alpha;
    float ar[4];
#pragma unroll
    for (int r = 0; r < 4; r++) ar[r] = __shfl(alpha, (quad << 2) + r, 64);
#pragma unroll
    for (int u = 0; u < 4; u++)
#pragma unroll
      for (int r = 0; r < 4; r++) o[u][r] *= ar[r];
  }

  // exp2 + tree sum (depth 4)
  float lnt[4];
#pragma unroll
  for (int nt = 0; nt < 4; nt++) {
#pragma unroll
    for (int r = 0; r < 4; r++)
      s[nt][r] = exp2v(s[nt][r] - m_i);
    lnt[nt] = (s[nt][0] + s[nt][1]) + (s[nt][2] + s[nt][3]);
  }
  float lsum = (lnt[0] + lnt[1]) + (lnt[2] + lnt[3]);
  lsum += __shfl_xor(lsum, 16, 64);
  lsum += __shfl_xor(lsum, 32, 64);
  l_i += lsum;
}

// P -> own-wave LDS (cvt_pk + b64 writes), then O += P V (vf already in regs).
__device__ __forceinline__ void fa_pv(
    u16* Pw, const float4v s[4], const short8 vf[2][4], float4v o[4],
    int quad, int l15) {
#pragma unroll
  for (int nt = 0; nt < 4; nt++) {
    const unsigned w0 = cvt_pk_bf16(s[nt][0], s[nt][1]);
    const unsigned w1 = cvt_pk_bf16(s[nt][2], s[nt][3]);
    uint2v ww; ww.x = w0; ww.y = w1;
    *(uint2v*)(Pw + l15 * 72 + nt * 16 + (quad << 2)) = ww;
  }
  __builtin_amdgcn_s_setprio(1);
#pragma unroll
  for (int ks = 0; ks < 2; ks++) {
    const short8 pf = *(const short8*)(Pw + l15 * 72 + ks * 32 + quad * 8);
#pragma unroll
    for (int u = 0; u < 4; u++)
      o[u] = __builtin_amdgcn_mfma_f32_16x16x32_bf16(pf, vf[ks][u], o[u], 0, 0, 0);
  }
  __builtin_amdgcn_s_setprio(0);
}

// ---------------------------------------------------------------------------
// Flash attention (causal), fused pair + XCD-local grid + single-buffered V
// (round 8 base). V^T now read from the permuted V-third of qkv (written by
// GEMM1's fused epilogue): physical row 2*(bh*64+hd)+(kt>>4), offset
// 2048+(kt&15)*64 within the row. Same swizzle/LDS pattern, address-only change.
// ---------------------------------------------------------------------------
__global__ __launch_bounds__(256) void flash_kernel(
    const u16* __restrict__ qkv, const float* __restrict__ am,
    u16* __restrict__ aout) {
  __shared__ u16 Ks[2][64 * 64];   // [key][slot], slot = chunk^(key&7), dbuf
  __shared__ u16 Vs[64 * 64];      // [hd][slot],  slot = chunk^(hd&7), single
  __shared__ u16 Ps[4][16 * 72];   // per-wave P [q=l15][key] (stride 72)

  const int tid = threadIdx.x, wave = tid >> 6, lane = tid & 63;
  const int bh = blockIdx.x, b = bh >> 4, h = bh & 15;   // XCD-local: id%8=bh%8
  const int qp = blockIdx.y;                             // 0..15
  const int qtA = qp, qtB = 31 - qp;                     // qtA < qtB always
  const size_t rowbase = (size_t)b * FA_S;
  const int quad = lane >> 4, l15 = lane & 15;
  const int lr = lane >> 3, lc = lane & 7;
  const int wq = wave * 16 + l15;      // q-local within a 64-row tile
  const float* amrow0 = am + b * FA_S;
  const u16* kbase = qkv + rowbase * FA_LD + FA_D + h * 64;

  // Q fragments for both tiles, pre-scaled by 1/8 (exact power of 2)
  short8 qfA[2], qfB[2];
#pragma unroll
  for (int t = 0; t < 2; t++) {
    const int qt = t ? qtB : qtA;
    const int qrow = qt * 64 + wq;
    const u16* qp_ = qkv + (rowbase + qrow) * FA_LD + h * 64 + quad * 8;
    __align__(16) u16 t0[8], t1[8];
    *(short8*)t0 = *(const short8*)qp_;
    *(short8*)t1 = *(const short8*)(qp_ + 32);
#pragma unroll
    for (int j = 0; j < 8; j++) {
      t0[j] = f2bf(bf2f(t0[j]) * 0.125f);
      t1[j] = f2bf(bf2f(t1[j]) * 0.125f);
    }
    if (t) { qfB[0] = *(const short8*)t0; qfB[1] = *(const short8*)t1; }
    else   { qfA[0] = *(const short8*)t0; qfA[1] = *(const short8*)t1; }
  }

  float mA = NEG_BIG, lA = 0.f, mB = NEG_BIG, lB = 0.f;
  float4v oA[4], oB[4];
#pragma unroll
  for (int u = 0; u < 4; u++) {
    oA[u] = (float4v){0.f, 0.f, 0.f, 0.f};
    oB[u] = (float4v){0.f, 0.f, 0.f, 0.f};
  }

  int cur = 0;
  // --- prologue: stage K tile kt=0 into buffer 0 ---
#pragma unroll
  for (int i = 0; i < 2; i++) {
    const int brow = wave * 16 + i * 8;
    const int row = brow + lr;
    const int cG = lc ^ (row & 7);
    __builtin_amdgcn_global_load_lds(
        (gas_p)(kbase + (size_t)row * FA_LD + cG * 8),
        (las_p)(Ks[0] + brow * 64), 16, 0, 0);
  }
  __syncthreads();   // drains vmcnt(0): K buffer 0 ready

  for (int kt = 0; kt <= qtB; kt++) {
    // --- stage V(kt) from the permuted V-third (Vs free: end barrier kt-1)
#pragma unroll
    for (int i = 0; i < 2; i++) {
      const int brow = wave * 16 + i * 8;
      const int row = brow + lr;                 // hd
      const int cG = lc ^ (row & 7);
      const u16* src = qkv + (size_t)(2 * (bh * 64 + row) + (kt >> 4)) * FA_LD
                     + 2048 + (kt & 15) * 64 + cG * 8;
      __builtin_amdgcn_global_load_lds((gas_p)src, (las_p)(Vs + brow * 64), 16, 0, 0);
    }
    // --- prefetch next K tile into Ks[cur^1] ---
    if (kt < qtB) {
#pragma unroll
      for (int i = 0; i < 2; i++) {
        const int brow = wave * 16 + i * 8;
        const int row = brow + lr;
        const int cG = lc ^ (row & 7);
        __builtin_amdgcn_global_load_lds(
            (gas_p)(kbase + (size_t)((kt + 1) * 64 + row) * FA_LD + cG * 8),
            (las_p)(Ks[cur ^ 1] + brow * 64), 16, 0, 0);
      }
    }
    const u16* Kc = Ks[cur];
    const bool actA = (kt <= qtA);   // wave-uniform

    // --- S^T = K Q^T for both tiles; each kf read feeds A and B ---
    float4v sA[4], sB[4];
#pragma unroll
    for (int nt = 0; nt < 4; nt++) {
      sA[nt] = (float4v){0.f, 0.f, 0.f, 0.f};
      sB[nt] = (float4v){0.f, 0.f, 0.f, 0.f};
    }
    __builtin_amdgcn_s_setprio(1);
#pragma unroll
    for (int ks = 0; ks < 2; ks++) {
#pragma unroll
      for (int nt = 0; nt < 4; nt++) {
        const int kr = nt * 16 + l15;
        const short8 kf = *(const short8*)(Kc + kr * 64 + (((ks * 4 + quad) ^ (kr & 7)) << 3));
        sB[nt] = __builtin_amdgcn_mfma_f32_16x16x32_bf16(kf, qfB[ks], sB[nt], 0, 0, 0);
        if (actA)
          sA[nt] = __builtin_amdgcn_mfma_f32_16x16x32_bf16(kf, qfA[ks], sA[nt], 0, 0, 0);
      }
    }
    __builtin_amdgcn_s_setprio(0);

    // --- softmax B (covers V/K load latency) ---
    const float* amrow = amrow0 + kt * 64;
    fa_softmax(sB, mB, lB, oB, amrow, kt == qtB, wq, quad);

    __syncthreads();   // drains vmcnt: Vs (and next-K) landed, all waves

    // --- V fragments from LDS, shared by both PV steps ---
    short8 vf[2][4];
#pragma unroll
    for (int ks = 0; ks < 2; ks++)
#pragma unroll
      for (int u = 0; u < 4; u++) {
        const int n = u * 16 + l15;
        vf[ks][u] = *(const short8*)(Vs + n * 64 + (((ks * 4 + quad) ^ (n & 7)) << 3));
      }

    if (actA) fa_softmax(sA, mA, lA, oA, amrow, kt == qtA, wq, quad);

    u16* Pw = Ps[wave];
    fa_pv(Pw, sB, vf, oB, quad, l15);            // P_B write -> PV_B
    if (actA) fa_pv(Pw, sA, vf, oA, quad, l15);  // reuse Pw (intra-wave order)

    __syncthreads();   // all waves done reading Vs & Ks[cur]
    cur ^= 1;
  }

  // --- epilogues (rcp instead of 16 divides) ---
#pragma unroll
  for (int t = 0; t < 2; t++) {
    const float l_i = t ? lB : lA;
    const float4v* o = t ? oB : oA;
    const int qrg = (t ? qtB : qtA) * 64 + wave * 16 + quad * 4;
    float li_[4];
#pragma unroll
    for (int r = 0; r < 4; r++) li_[r] = rcpv(__shfl(l_i, (quad << 2) + r, 64));
#pragma unroll
    for (int u = 0; u < 4; u++) {
      const int col = h * 64 + u * 16 + l15;
#pragma unroll
      for (int r = 0; r < 4; r++) {
        const float val = o[u][r] * li_[r];
        aout[(rowbase + qrg + r) * FA_D + col] = f2bf(val);
      }
    }
  }
}

// ---------------------------------------------------------------------------
extern "C" void kernel_launch(void* const* d_in, const int* in_sizes, int n_in,
                              void* d_out, int out_size, void* d_ws, size_t ws_size,
                              hipStream_t stream) {
  (void)out_size; (void)ws_size;
  auto find = [&](int count, int def_idx) -> const void* {
    for (int i = 0; i < n_in; i++)
      if (in_sizes[i] == count) return d_in[i];
    return d_in[def_idx];
  };
  const void* x  = find(8388608, 0);
  const void* am = find(8192, 1);
  const void* Wa = find(3145728, 2);
  const void* ba = find(3072, 3);
  const void* Wp = find(1048576, 4);
  const void* bp = find(1024, 5);

  char* ws = (char*)d_ws;
  u16*   x_c  = (u16*)(ws + 0);
  u16*   Wa_t = (u16*)(ws + 16777216);
  u16*   Wp_t = (u16*)(ws + 23068672);
  u16*   qkv  = (u16*)(ws + 25165824);
  u16*   abuf = (u16*)(ws + 75497472);
  float* ba_f = (float*)(ws + 92274688);
  float* bp_f = (float*)(ws + 92286976);
  float* am_f = (float*)(ws + 92291072);
  int*   flag = (int*)(ws + 92323840);

  const int M = 8192, D = 1024;

  detect_kernel<<<1, 256, 0, stream>>>((const u16*)x, flag);
  cvt_bf16_kernel<<<2048, 256, 0, stream>>>(x, flag, x_c, M * D);
  cvt_f32_kernel<<<12, 256, 0, stream>>>(ba, flag, ba_f, 3072, 1.0f);
  cvt_f32_kernel<<<4, 256, 0, stream>>>(bp, flag, bp_f, 1024, 1.0f);
  cvt_f32_kernel<<<32, 256, 0, stream>>>(am, flag, am_f, 4 * FA_S, L2E);  // log2e domain
  cvt_transpose_kernel<<<dim3(3072 / 64, 1024 / 64), 256, 0, stream>>>(Wa, flag, Wa_t, 1024, 3072);
  cvt_transpose_kernel<<<dim3(1024 / 64, 1024 / 64), 256, 0, stream>>>(Wp, flag, Wp_t, 1024, 1024);

  // GEMM1 with fused V-transpose epilogue (vfuse=1): V-cols written permuted
  // into qkv's own V-third; vtrans kernel eliminated.
  gemm_bt_kernel<<<dim3(3072 / 128, M / 128), 256, 0, stream>>>(
      x_c, Wa_t, ba_f, qkv, M, 3072, D, 0, 1);
  // grid x=bh (64), y=qp (16): wg id % 8 == bh % 8 -> per-bh XCD locality
  flash_kernel<<<dim3(64, 16), 256, 0, stream>>>(qkv, am_f, abuf);
  gemm_bt_kernel<<<dim3(D / 128, M / 128), 256, 0, stream>>>(
      abuf, Wp_t, bp_f, d_out, M, D, D, 1, 0);
}